// Round 9
// baseline (285.598 us; speedup 1.0000x reference)
//
#include <hip/hip_runtime.h>

// B=4, S=2048, D=E=1024, DIM=64 -> scale 0.125
// softmax quirk: normalized over the QUERY axis:
//   attn[b,q,k] = exp(s[b,q,k] - m[b,k]) / sum_q' exp(s[b,q',k] - m[b,k])
//
// R9: per-phase interleaved 8-phase counted-vmcnt GEMM (m201-faithful):
// each phase: {4 ds_read a-frags (+8 b at ph1/ph5) || 1 half-tile stage ||
// barrier || lgkmcnt(0)+sched_barrier || setprio(1) MFMA-quadrant setprio(0)
// || barrier}. Stage order A(T+1)@ph1-2, B(T+2)@ph3-4, A(T+2)@ph5-6,
// B(T+3)@ph7-8 (each half overwrites only post-barrier-consumed data).
// vmcnt(4) [BN=256] / vmcnt(2) [BN=128] at ph4/ph8. Tail-clamped stages keep
// issue counts uniform. Pipeline: Wvo fold; batched {Q,K,VWo} proj; fp16
// scores; softmax-over-q stats + in-place normalize; final attn@VWo.

typedef _Float16 f16;
typedef _Float16 f16x8 __attribute__((ext_vector_type(8)));
typedef float f32x4 __attribute__((ext_vector_type(4)));

__device__ __forceinline__ void gl_lds16(const void* g, void* l) {
  __builtin_amdgcn_global_load_lds(
      (const __attribute__((address_space(1))) void*)(uintptr_t)g,
      (__attribute__((address_space(3))) void*)(uint32_t)(uintptr_t)l, 16, 0, 0);
}

#define BARR __builtin_amdgcn_s_barrier()
#define PRIO1 __builtin_amdgcn_s_setprio(1)
#define PRIO0 __builtin_amdgcn_s_setprio(0)
#define LGKM0                                          \
  do {                                                 \
    asm volatile("s_waitcnt lgkmcnt(0)" ::: "memory"); \
    __builtin_amdgcn_sched_barrier(0);                 \
  } while (0)

// one C-quadrant (m-pair Q) x K=64: 2m x NF n x 2kk MFMAs, a[] is per-phase
#define MFQ(Q)                                                             \
  {                                                                        \
    _Pragma("unroll") for (int mm = 0; mm < 2; ++mm)                       \
        _Pragma("unroll") for (int n = 0; n < NF; ++n)                     \
            _Pragma("unroll") for (int kk = 0; kk < 2; ++kk)               \
                acc[(Q)*2 + mm][n] = __builtin_amdgcn_mfma_f32_16x16x32_f16( \
                    a[mm * 2 + kk], b[n * 2 + kk], acc[(Q)*2 + mm][n], 0, 0, 0); \
  }

// C[M,N] = scale * A[M,K]*B[N,K]^T  (NT layout, fp16 in, fp32 accum)
// EPI: 0 = fp32 C; 2 = fp16 C; 4 = fp16 C, z==2 written per-batch transposed
//      (projection batch: Q, K, VWo^T).
template <int BN, int EPI>
__global__ __launch_bounds__(512, 2) void gemm256(
    const f16* __restrict__ Ag, const f16* __restrict__ Bg,
    float* __restrict__ Cf, f16* __restrict__ Ch,
    int K, int ldA, int ldB, int ldC, long sA, long sB, long sC, float scale) {
  constexpr int NF = BN / 64;        // b-frags per wave
  constexpr int LB = BN / 128;       // gl_lds loads per B-half
  constexpr int AH = 128 * 64;       // f16 per A-half
  constexpr int BH = (BN / 2) * 64;  // f16 per B-half
  constexpr int DB = 2 * AH + 2 * BH;
  __shared__ f16 lds[2 * DB];

  const int tid = threadIdx.x;
  const int lane = tid & 63;
  const int wave = tid >> 6;
  const long bz = blockIdx.z;
  const int tM = blockIdx.y * 256;
  const int tN = blockIdx.x * BN;
  const int wr = wave >> 2;   // 0..1  (A-half)
  const int wc = wave & 3;    // 0..3
  const int r16 = lane & 15;
  const int q4 = lane >> 4;

  const f16* Abase = Ag + bz * sA;
  const f16* Bbase = Bg + bz * sB;
  const int NT = K >> 6;

  f16x8 a[4];        // per-phase a-frags (reused)
  f16x8 b[2 * NF];   // per-K-tile b-frags
  f32x4 acc[8][NF] = {};

  // Clamped stage: for t >= NT re-stage t-2 (same parity/dbuf, consumed) so
  // gl_lds issue counts are IDENTICAL every iteration (vmcnt stays valid).
  auto stA = [&](int t, int half) {
    int tc = (t < NT) ? t : (t - 2);
    f16* dst = lds + (t & 1) * DB + half * AH;
    const f16* g = Abase + (long)(tM + half * 128) * ldA + tc * 64;
#pragma unroll
    for (int l = 0; l < 2; ++l) {
      int r = l * 64 + wave * 8 + (lane >> 3);
      int s = lane & 7;
      gl_lds16(g + (long)r * ldA + ((s ^ (r & 7)) << 3), dst + r * 64 + s * 8);
    }
  };
  auto stB = [&](int t, int half) {
    int tc = (t < NT) ? t : (t - 2);
    f16* dst = lds + (t & 1) * DB + 2 * AH + half * BH;
    const f16* g = Bbase + (long)(tN + half * (BN / 2)) * ldB + tc * 64;
#pragma unroll
    for (int l = 0; l < LB; ++l) {
      int r = l * 64 + wave * 8 + (lane >> 3);
      int s = lane & 7;
      gl_lds16(g + (long)r * ldB + ((s ^ (r & 7)) << 3), dst + r * 64 + s * 8);
    }
  };
  // per-phase fragment loads (a: m-pair mq of tile t; b: all n-frags)
  auto ldsA = [&](int t, int mq) {
    const f16* ah = lds + (t & 1) * DB + wr * AH;
#pragma unroll
    for (int mm = 0; mm < 2; ++mm)
#pragma unroll
      for (int kk = 0; kk < 2; ++kk) {
        int arl = (mq * 2 + mm) * 16 + r16;
        a[mm * 2 + kk] =
            *(const f16x8*)(ah + arl * 64 + ((((kk << 2) + q4) ^ (arl & 7)) << 3));
      }
  };
  auto ldsB = [&](int t) {
    const f16* db = lds + (t & 1) * DB;
#pragma unroll
    for (int n = 0; n < NF; ++n)
#pragma unroll
      for (int kk = 0; kk < 2; ++kk) {
        int colg = wc * (BN / 4) + n * 16 + r16;
        const f16* bh = db + 2 * AH + (colg / (BN / 2)) * BH;
        int brl = colg % (BN / 2);
        b[n * 2 + kk] =
            *(const f16x8*)(bh + brl * 64 + ((((kk << 2) + q4) ^ (brl & 7)) << 3));
      }
  };

#define VMW                                            \
  do {                                                 \
    if constexpr (BN == 256)                           \
      asm volatile("s_waitcnt vmcnt(4)" ::: "memory"); \
    else                                               \
      asm volatile("s_waitcnt vmcnt(2)" ::: "memory"); \
  } while (0)

  // prologue: tile0 all halves, then B halves of tile1; drain tile0.
  stA(0, 0); stA(0, 1); stB(0, 0); stB(0, 1);
  stB(1, 0); stB(1, 1);
  VMW;
  BARR;

  for (int T = 0; T < NT; T += 2) {
    // ---- tile T (dbuf0) ----
    ldsB(T); ldsA(T, 0);
    stA(T + 1, 0);
    BARR; LGKM0; PRIO1; MFQ(0); PRIO0; BARR;
    ldsA(T, 1);
    stA(T + 1, 1);
    BARR; LGKM0; PRIO1; MFQ(1); PRIO0; BARR;
    ldsA(T, 2);
    stB(T + 2, 0);
    BARR; LGKM0; PRIO1; MFQ(2); PRIO0; BARR;
    ldsA(T, 3);
    stB(T + 2, 1);
    BARR; LGKM0; PRIO1; MFQ(3); PRIO0; VMW; BARR;
    // ---- tile T+1 (dbuf1) ----
    ldsB(T + 1); ldsA(T + 1, 0);
    stA(T + 2, 0);
    BARR; LGKM0; PRIO1; MFQ(0); PRIO0; BARR;
    ldsA(T + 1, 1);
    stA(T + 2, 1);
    BARR; LGKM0; PRIO1; MFQ(1); PRIO0; BARR;
    ldsA(T + 1, 2);
    stB(T + 3, 0);
    BARR; LGKM0; PRIO1; MFQ(2); PRIO0; BARR;
    ldsA(T + 1, 3);
    stB(T + 3, 1);
    BARR; LGKM0; PRIO1; MFQ(3); PRIO0; VMW; BARR;
  }
#undef VMW

#pragma unroll
  for (int m = 0; m < 8; ++m)
#pragma unroll
    for (int n = 0; n < NF; ++n)
#pragma unroll
      for (int j = 0; j < 4; ++j) {
        int rr = tM + wr * 128 + m * 16 + q4 * 4 + j;
        int cc = tN + wc * (BN / 4) + n * 16 + r16;
        float v = acc[m][n][j] * scale;
        if constexpr (EPI == 0) {
          Cf[bz * sC + (long)rr * ldC + cc] = v;
        } else if constexpr (EPI == 2) {
          Ch[bz * sC + (long)rr * ldC + cc] = (f16)v;
        } else {  // EPI == 4
          if (bz == 2)
            Ch[2 * sC + (long)cc * 2048 + (long)(rr >> 11) * 2097152L + (rr & 2047)] = (f16)v;
          else
            Ch[bz * sC + (long)rr * ldC + cc] = (f16)v;
        }
      }
}

// small 128x128-tile GEMM for Wvo = (Wv @ Wo)^T  (fp16, transposed store)
__global__ __launch_bounds__(256) void gemm_wvo(
    const f16* __restrict__ Ag, const f16* __restrict__ Bg, f16* __restrict__ Ch,
    int K, int ldA, int ldB, int ldC) {
  __shared__ f16 sA_[128 * 64];
  __shared__ f16 sB_[128 * 64];
  const int tid = threadIdx.x;
  const int lane = tid & 63;
  const int wave = tid >> 6;
  const int tM = blockIdx.y * 128;
  const int tN = blockIdx.x * 128;
  const int wr = (wave >> 1) * 64;
  const int wc = (wave & 1) * 64;
  const int r16 = lane & 15;
  const int q4 = lane >> 4;
  f32x4 acc[4][4] = {};
  for (int kt = 0; kt < K; kt += 64) {
#pragma unroll
    for (int it = 0; it < 4; ++it) {
      int row = it * 32 + (tid >> 3);
      int s = tid & 7;
      int gcol = kt + ((s ^ (row & 7)) << 3);
      int lo = row * 64 + s * 8;
      gl_lds16(Ag + (long)(tM + row) * ldA + gcol, sA_ + lo);
      gl_lds16(Bg + (long)(tN + row) * ldB + gcol, sB_ + lo);
    }
    __syncthreads();
#pragma unroll
    for (int kk = 0; kk < 2; ++kk) {
      f16x8 ah[4], bh[4];
#pragma unroll
      for (int m = 0; m < 4; ++m) {
        int ar = wr + m * 16 + r16;
        ah[m] = *(const f16x8*)(sA_ + ar * 64 + (((kk * 4 + q4) ^ (ar & 7)) << 3));
      }
#pragma unroll
      for (int n = 0; n < 4; ++n) {
        int br = wc + n * 16 + r16;
        bh[n] = *(const f16x8*)(sB_ + br * 64 + (((kk * 4 + q4) ^ (br & 7)) << 3));
      }
#pragma unroll
      for (int m = 0; m < 4; ++m)
#pragma unroll
        for (int n = 0; n < 4; ++n)
          acc[m][n] = __builtin_amdgcn_mfma_f32_16x16x32_f16(ah[m], bh[n], acc[m][n], 0, 0, 0);
    }
    __syncthreads();
  }
#pragma unroll
  for (int m = 0; m < 4; ++m)
#pragma unroll
    for (int n = 0; n < 4; ++n)
#pragma unroll
      for (int j = 0; j < 4; ++j) {
        int rr = tM + wr + m * 16 + q4 * 4 + j;
        int cc = tN + wc + n * 16 + r16;
        Ch[(long)cc * ldC + rr] = (f16)acc[m][n][j];
      }
}

// fp32 -> fp16 conversion, 8 elems/thread
__global__ __launch_bounds__(256) void convert(const float* __restrict__ in,
                                               f16* __restrict__ hi, long n) {
  long i = ((long)blockIdx.x * 256 + threadIdx.x) * 8;
  if (i >= n) return;
  float4 aa = *(const float4*)(in + i);
  float4 bb = *(const float4*)(in + i + 4);
  f16x8 h;
  h[0] = (f16)aa.x; h[1] = (f16)aa.y; h[2] = (f16)aa.z; h[3] = (f16)aa.w;
  h[4] = (f16)bb.x; h[5] = (f16)bb.y; h[6] = (f16)bb.z; h[7] = (f16)bb.w;
  *(f16x8*)(hi + i) = h;
}

// transpose + fp16 convert (n x n)
__global__ void tconv(const float* __restrict__ in, f16* __restrict__ hi, int n) {
  __shared__ float t[32][33];
  int bx = blockIdx.x * 32, by = blockIdx.y * 32;
  int tx = threadIdx.x, ty = threadIdx.y;  // 32 x 8
  for (int i = 0; i < 32; i += 8) t[ty + i][tx] = in[(long)(by + ty + i) * n + bx + tx];
  __syncthreads();
  for (int i = 0; i < 32; i += 8)
    hi[(long)(bx + ty + i) * n + by + tx] = (f16)t[tx][ty + i];
}

// per-column (over q) online max/sum from fp16 S; 32-row chunks, 8 cols/thread
__global__ __launch_bounds__(256) void stats1(const f16* __restrict__ S16,
                                              float* __restrict__ pm, float* __restrict__ pl) {
  int b = blockIdx.z;
  int q0 = blockIdx.y * 32;
  int c0 = threadIdx.x * 8;
  const f16* Sb = S16 + (long)b * 4194304;
  float m[8], l[8];
#pragma unroll
  for (int j = 0; j < 8; ++j) { m[j] = -1e30f; l[j] = 0.f; }
  for (int i = 0; i < 32; ++i) {
    f16x8 v = *(const f16x8*)(Sb + (long)(q0 + i) * 2048 + c0);
#pragma unroll
    for (int j = 0; j < 8; ++j) {
      float s = (float)v[j];
      float mn = fmaxf(m[j], s);
      l[j] = l[j] * __expf(m[j] - mn) + __expf(s - mn);
      m[j] = mn;
    }
  }
  int base = (b * 64 + blockIdx.y) * 2048 + c0;
#pragma unroll
  for (int j = 0; j < 8; ++j) { pm[base + j] = m[j]; pl[base + j] = l[j]; }
}

__global__ void stats2(const float* __restrict__ pm, const float* __restrict__ pl,
                       float* __restrict__ mfo, float* __restrict__ rlo) {
  int c = blockIdx.x * 256 + threadIdx.x;  // b*2048 + k
  int b = c >> 11, k = c & 2047;
  float m = -1e30f;
  for (int qc = 0; qc < 64; ++qc) m = fmaxf(m, pm[(b * 64 + qc) * 2048 + k]);
  float l = 0.f;
  for (int qc = 0; qc < 64; ++qc)
    l += pl[(b * 64 + qc) * 2048 + k] * __expf(pm[(b * 64 + qc) * 2048 + k] - m);
  mfo[c] = m;
  rlo[c] = 1.f / l;
}

// in-place: S16 <- exp(S16 - m[col]) * rl[col]   (fp16)
__global__ __launch_bounds__(256) void norm(f16* __restrict__ S16,
                                            const float* __restrict__ mf,
                                            const float* __restrict__ rl) {
  long row = blockIdx.x;  // b*2048 + q
  int b = (int)(row >> 11);
  f16* Sr = S16 + row * 2048;
  const float* mb = mf + ((long)b << 11);
  const float* rb = rl + ((long)b << 11);
  int c = threadIdx.x * 8;
  f16x8 v = *(f16x8*)(Sr + c);
  float4 m0 = *(const float4*)(mb + c);
  float4 m1 = *(const float4*)(mb + c + 4);
  float4 r0 = *(const float4*)(rb + c);
  float4 r1 = *(const float4*)(rb + c + 4);
  f16x8 o;
  o[0] = (f16)(__expf((float)v[0] - m0.x) * r0.x);
  o[1] = (f16)(__expf((float)v[1] - m0.y) * r0.y);
  o[2] = (f16)(__expf((float)v[2] - m0.z) * r0.z);
  o[3] = (f16)(__expf((float)v[3] - m0.w) * r0.w);
  o[4] = (f16)(__expf((float)v[4] - m1.x) * r1.x);
  o[5] = (f16)(__expf((float)v[5] - m1.y) * r1.y);
  o[6] = (f16)(__expf((float)v[6] - m1.z) * r1.z);
  o[7] = (f16)(__expf((float)v[7] - m1.w) * r1.w);
  *(f16x8*)(Sr + c) = o;
}

extern "C" void kernel_launch(void* const* d_in, const int* in_sizes, int n_in,
                              void* d_out, int out_size, void* d_ws, size_t ws_size,
                              hipStream_t stream) {
  const float* query = (const float*)d_in[0];
  const float* key   = (const float*)d_in[1];
  const float* value = (const float*)d_in[2];
  const float* Wq    = (const float*)d_in[3];
  const float* Wk    = (const float*)d_in[4];
  const float* Wv    = (const float*)d_in[5];
  const float* Wo    = (const float*)d_in[6];
  float* out = (float*)d_out;

  // arena (f16-element offsets), ~144 MB
  f16* h = (f16*)d_ws;
  const long E8 = 8388608L;  // 8192*1024
  const long E1 = 1048576L;  // 1024*1024
  f16* q16   = h;            // contiguous A-batch for proj: q16,k16,v16
  f16* k16   = h + E8;
  f16* v16   = h + 2 * E8;
  f16* Qh    = h + 3 * E8;   // contiguous C-batch: Qh, Kh, VWoT
  f16* Kh    = h + 4 * E8;
  f16* VWoT  = h + 5 * E8;   // [4][1024][2048]
  f16* Wqt   = h + 6 * E8;   // contiguous B-batch: Wqt, Wkt, Wvot
  f16* Wkt   = Wqt + E1;
  f16* Wvot  = Wkt + E1;
  f16* Wot   = Wvot + E1;
  f16* wv16  = Wot + E1;
  f16* S16   = wv16 + E1;    // [4][2048][2048] fp16 scores -> attn (in place)
  float* pm  = (float*)(S16 + 16777216L);  // [4][64][2048]
  float* pl  = pm + 524288;
  float* mf  = pl + 524288;  // 8192
  float* rl  = mf + 8192;
  (void)in_sizes; (void)n_in; (void)out_size; (void)ws_size;

  dim3 tb32(32, 8);
  tconv<<<dim3(32, 32), tb32, 0, stream>>>(Wq, Wqt, 1024);
  tconv<<<dim3(32, 32), tb32, 0, stream>>>(Wk, Wkt, 1024);
  tconv<<<dim3(32, 32), tb32, 0, stream>>>(Wo, Wot, 1024);
  convert<<<512, 256, 0, stream>>>(Wv, wv16, E1);

  // Wvo^T = (Wv @ Wo)^T  (M=N=K=1024)
  gemm_wvo<<<dim3(8, 8, 1), 256, 0, stream>>>(wv16, Wot, Wvot, 1024, 1024, 1024, 1024);

  // input conversions
  convert<<<4096, 256, 0, stream>>>(query, q16, E8);
  convert<<<4096, 256, 0, stream>>>(key, k16, E8);
  convert<<<4096, 256, 0, stream>>>(value, v16, E8);

  // batched projections z=3: z0 Q=query@Wq, z1 K=key@Wk, z2 VWo=value@Wvo
  // (z2 written per-batch transposed: VWoT[b][e][s]) -- 384 blocks
  gemm256<256, 4><<<dim3(4, 32, 3), 512, 0, stream>>>(
      q16, Wqt, nullptr, Qh, 1024, 1024, 1024, 1024, E8, E1, E8, 1.f);

  // scores = 0.125 * Q K^T per batch (M=N=2048, K=1024), fp16 out -- 256 blocks
  gemm256<256, 2><<<dim3(8, 8, 4), 512, 0, stream>>>(
      Qh, Kh, nullptr, S16, 1024, 1024, 1024, 2048, 2097152L, 2097152L, 4194304L, 0.125f);

  // softmax-over-q stats from fp16 S, then normalize in place
  stats1<<<dim3(1, 64, 4), 256, 0, stream>>>(S16, pm, pl);
  stats2<<<32, 256, 0, stream>>>(pm, pl, mf, rl);
  norm<<<8192, 256, 0, stream>>>(S16, mf, rl);

  // out = attn @ VWo per batch (M=2048, N=1024, K=2048), fp32 out -- 256 blocks
  gemm256<128, 0><<<dim3(8, 8, 4), 512, 0, stream>>>(
      S16, VWoT, out, nullptr, 2048, 2048, 2048, 1024, 4194304L, 2097152L, 2097152L, 1.f);
}

// Round 10
// 264.420 us; speedup vs baseline: 1.0801x; 1.0801x over previous
//
#include <hip/hip_runtime.h>

// B=4, S=2048, D=E=1024, DIM=64 -> scale 0.125
// softmax quirk: normalized over the QUERY axis:
//   attn[b,q,k] = exp(s[b,q,k] - m[b,k]) / sum_q' exp(s[b,q',k] - m[b,k])
//
// R10: proven 2-phase 128x128 BK=64 conflict-free gemm16 for ALL GEMMs +
// (a) XCD-chunked bijective block swizzle (T1/m204) for L2 panel reuse,
// (b) column-stats (max, sumexp over q) fused into the scores epilogue
//     (shfl_xor q4-reduce + LDS cross-wave merge -> pm/pl[4][16][2048]),
// (c) fused z=3 transpose-convert and z=3 input-convert kernels.
// Pipeline: Wvo=Wv@Wo fold (out = attn @ (value@Wvo)); batched {Q,K,VWo}
// proj; fp16 scores (+fused stats); stats2; in-place norm; final attn@VWo.

typedef _Float16 f16;
typedef _Float16 f16x8 __attribute__((ext_vector_type(8)));
typedef float f32x4 __attribute__((ext_vector_type(4)));

__device__ __forceinline__ void gl_lds16(const void* g, void* l) {
  __builtin_amdgcn_global_load_lds(
      (const __attribute__((address_space(1))) void*)(uintptr_t)g,
      (__attribute__((address_space(3))) void*)(uint32_t)(uintptr_t)l, 16, 0, 0);
}

// bijective XCD-chunked swizzle (m204): consecutive work ids -> same XCD
__device__ __forceinline__ int xcd_swz(int F, int nwg) {
  int q = nwg >> 3, r = nwg & 7;
  int xcd = F & 7, idx = F >> 3;
  return (xcd < r ? xcd * (q + 1) : r * (q + 1) + (xcd - r) * q) + idx;
}

// C[M,N] = scale * A[M,K]*B[N,K]^T  (NT, fp16 operands, fp32 accum)
// EPI: 0 = fp32 C; 2 = fp16 C; 4 = fp16 C, z==2 written per-batch transposed
//      (projection batch: Q, K, VWo^T).
// STATS: fused per-block column stats (max, sumexp over the 128 q-rows).
template <int EPI, int STATS>
__global__ __launch_bounds__(256) void gemm16(
    const f16* __restrict__ Ag, const f16* __restrict__ Bg,
    float* __restrict__ Cf, f16* __restrict__ Ch,
    float* __restrict__ pm, float* __restrict__ pl,
    int K, int ldA, int ldB, int ldC, long sA, long sB, long sC, float scale) {
  __shared__ f16 sA_[128 * 64];
  __shared__ f16 sB_[128 * 64];

  const int tid = threadIdx.x;
  const int lane = tid & 63;
  const int wave = tid >> 6;
  // swizzled block coordinates
  const int gx = gridDim.x, gy = gridDim.y;
  const int nwg = gx * gy * gridDim.z;
  int F = blockIdx.x + gx * (blockIdx.y + gy * blockIdx.z);
  int wg = xcd_swz(F, nwg);
  const int bx = wg % gx;
  const int by = (wg / gx) % gy;
  const long bz = wg / (gx * gy);

  const int tM = by * 128;
  const int tN = bx * 128;
  const int wr = (wave >> 1) * 64;
  const int wc = (wave & 1) * 64;
  const int r16 = lane & 15;
  const int q4 = lane >> 4;

  const f16* Abase = Ag + bz * sA;
  const f16* Bbase = Bg + bz * sB;

  f32x4 acc[4][4] = {};

  for (int kt = 0; kt < K; kt += 64) {
    // stage A,B tiles [128][64]; LDS linear dest, source col pre-swizzled
#pragma unroll
    for (int it = 0; it < 4; ++it) {
      int row = it * 32 + (tid >> 3);
      int s = tid & 7;
      int gcol = kt + ((s ^ (row & 7)) << 3);
      int lo = row * 64 + s * 8;
      gl_lds16(Abase + (long)(tM + row) * ldA + gcol, sA_ + lo);
      gl_lds16(Bbase + (long)(tN + row) * ldB + gcol, sB_ + lo);
    }
    __syncthreads();
#pragma unroll
    for (int kk = 0; kk < 2; ++kk) {
      f16x8 ah[4], bh[4];
#pragma unroll
      for (int m = 0; m < 4; ++m) {
        int ar = wr + m * 16 + r16;
        ah[m] = *(const f16x8*)(sA_ + ar * 64 + (((kk * 4 + q4) ^ (ar & 7)) << 3));
      }
#pragma unroll
      for (int n = 0; n < 4; ++n) {
        int br = wc + n * 16 + r16;
        bh[n] = *(const f16x8*)(sB_ + br * 64 + (((kk * 4 + q4) ^ (br & 7)) << 3));
      }
#pragma unroll
      for (int m = 0; m < 4; ++m)
#pragma unroll
        for (int n = 0; n < 4; ++n)
          acc[m][n] = __builtin_amdgcn_mfma_f32_16x16x32_f16(ah[m], bh[n], acc[m][n], 0, 0, 0);
    }
    __syncthreads();
  }

  // C write
#pragma unroll
  for (int m = 0; m < 4; ++m)
#pragma unroll
    for (int n = 0; n < 4; ++n)
#pragma unroll
      for (int j = 0; j < 4; ++j) {
        int rr = tM + wr + m * 16 + q4 * 4 + j;
        int cc = tN + wc + n * 16 + r16;
        float v = acc[m][n][j] * scale;
        if constexpr (EPI == 0) {
          Cf[bz * sC + (long)rr * ldC + cc] = v;
        } else if constexpr (EPI == 2) {
          Ch[bz * sC + (long)rr * ldC + cc] = (f16)v;
        } else {  // EPI == 4: projection batch
          if (bz == 2)
            Ch[2 * sC + (long)cc * 2048 + (long)(rr >> 11) * 2097152L + (rr & 2047)] = (f16)v;
          else
            Ch[bz * sC + (long)rr * ldC + cc] = (f16)v;
        }
      }

  if constexpr (STATS) {
    // per-block column stats over the 128 rows, for 128 cols.
    float* mbuf = (float*)sA_;        // [2][128]
    float* lbuf = mbuf + 256;
    const int wrIdx = wave >> 1, c0 = wc;
#pragma unroll
    for (int n = 0; n < 4; ++n) {
      float mt = -1e30f;
#pragma unroll
      for (int m = 0; m < 4; ++m)
#pragma unroll
        for (int j = 0; j < 4; ++j) mt = fmaxf(mt, acc[m][n][j] * scale);
      float lt = 0.f;
#pragma unroll
      for (int m = 0; m < 4; ++m)
#pragma unroll
        for (int j = 0; j < 4; ++j) lt += __expf(acc[m][n][j] * scale - mt);
      // reduce over q4 (lanes xor 16, 32): online merge
#pragma unroll
      for (int d = 16; d <= 32; d <<= 1) {
        float mo = __shfl_xor(mt, d);
        float lo = __shfl_xor(lt, d);
        float mn = fmaxf(mt, mo);
        lt = lt * __expf(mt - mn) + lo * __expf(mo - mn);
        mt = mn;
      }
      if (q4 == 0) {
        int c = c0 + n * 16 + r16;
        mbuf[wrIdx * 128 + c] = mt;
        lbuf[wrIdx * 128 + c] = lt;
      }
    }
    __syncthreads();
    if (tid < 128) {
      float m0 = mbuf[tid], m1 = mbuf[128 + tid];
      float l0 = lbuf[tid], l1 = lbuf[128 + tid];
      float mn = fmaxf(m0, m1);
      float ln = l0 * __expf(m0 - mn) + l1 * __expf(m1 - mn);
      long idx = (bz * 16 + (tM >> 7)) * 2048 + tN + tid;
      pm[idx] = mn;
      pl[idx] = ln;
    }
  }
}

// small 128x128-tile GEMM for Wvo = (Wv @ Wo)^T  (fp16, transposed store)
__global__ __launch_bounds__(256) void gemm_wvo(
    const f16* __restrict__ Ag, const f16* __restrict__ Bg, f16* __restrict__ Ch,
    int K, int ldA, int ldB, int ldC) {
  __shared__ f16 sA_[128 * 64];
  __shared__ f16 sB_[128 * 64];
  const int tid = threadIdx.x;
  const int lane = tid & 63;
  const int wave = tid >> 6;
  const int tM = blockIdx.y * 128;
  const int tN = blockIdx.x * 128;
  const int wr = (wave >> 1) * 64;
  const int wc = (wave & 1) * 64;
  const int r16 = lane & 15;
  const int q4 = lane >> 4;
  f32x4 acc[4][4] = {};
  for (int kt = 0; kt < K; kt += 64) {
#pragma unroll
    for (int it = 0; it < 4; ++it) {
      int row = it * 32 + (tid >> 3);
      int s = tid & 7;
      int gcol = kt + ((s ^ (row & 7)) << 3);
      int lo = row * 64 + s * 8;
      gl_lds16(Ag + (long)(tM + row) * ldA + gcol, sA_ + lo);
      gl_lds16(Bg + (long)(tN + row) * ldB + gcol, sB_ + lo);
    }
    __syncthreads();
#pragma unroll
    for (int kk = 0; kk < 2; ++kk) {
      f16x8 ah[4], bh[4];
#pragma unroll
      for (int m = 0; m < 4; ++m) {
        int ar = wr + m * 16 + r16;
        ah[m] = *(const f16x8*)(sA_ + ar * 64 + (((kk * 4 + q4) ^ (ar & 7)) << 3));
      }
#pragma unroll
      for (int n = 0; n < 4; ++n) {
        int br = wc + n * 16 + r16;
        bh[n] = *(const f16x8*)(sB_ + br * 64 + (((kk * 4 + q4) ^ (br & 7)) << 3));
      }
#pragma unroll
      for (int m = 0; m < 4; ++m)
#pragma unroll
        for (int n = 0; n < 4; ++n)
          acc[m][n] = __builtin_amdgcn_mfma_f32_16x16x32_f16(ah[m], bh[n], acc[m][n], 0, 0, 0);
    }
    __syncthreads();
  }
#pragma unroll
  for (int m = 0; m < 4; ++m)
#pragma unroll
    for (int n = 0; n < 4; ++n)
#pragma unroll
      for (int j = 0; j < 4; ++j) {
        int rr = tM + wr + m * 16 + q4 * 4 + j;
        int cc = tN + wc + n * 16 + r16;
        Ch[(long)cc * ldC + rr] = (f16)acc[m][n][j];
      }
}

// fused fp32 -> fp16 conversion for q,k,v (z selects buffer)
__global__ __launch_bounds__(256) void convert3(
    const float* __restrict__ i0, const float* __restrict__ i1,
    const float* __restrict__ i2, f16* __restrict__ o0, f16* __restrict__ o1,
    f16* __restrict__ o2, long n) {
  const float* in = (blockIdx.z == 0) ? i0 : (blockIdx.z == 1) ? i1 : i2;
  f16* hi = (blockIdx.z == 0) ? o0 : (blockIdx.z == 1) ? o1 : o2;
  long i = ((long)blockIdx.x * 256 + threadIdx.x) * 8;
  if (i >= n) return;
  float4 aa = *(const float4*)(in + i);
  float4 bb = *(const float4*)(in + i + 4);
  f16x8 h;
  h[0] = (f16)aa.x; h[1] = (f16)aa.y; h[2] = (f16)aa.z; h[3] = (f16)aa.w;
  h[4] = (f16)bb.x; h[5] = (f16)bb.y; h[6] = (f16)bb.z; h[7] = (f16)bb.w;
  *(f16x8*)(hi + i) = h;
}

__global__ __launch_bounds__(256) void convert1(const float* __restrict__ in,
                                                f16* __restrict__ hi, long n) {
  long i = ((long)blockIdx.x * 256 + threadIdx.x) * 8;
  if (i >= n) return;
  float4 aa = *(const float4*)(in + i);
  float4 bb = *(const float4*)(in + i + 4);
  f16x8 h;
  h[0] = (f16)aa.x; h[1] = (f16)aa.y; h[2] = (f16)aa.z; h[3] = (f16)aa.w;
  h[4] = (f16)bb.x; h[5] = (f16)bb.y; h[6] = (f16)bb.z; h[7] = (f16)bb.w;
  *(f16x8*)(hi + i) = h;
}

// fused transpose + fp16 convert for Wq,Wk,Wo (z selects)
__global__ void tconv3(const float* __restrict__ i0, const float* __restrict__ i1,
                       const float* __restrict__ i2, f16* __restrict__ o0,
                       f16* __restrict__ o1, f16* __restrict__ o2, int n) {
  const float* in = (blockIdx.z == 0) ? i0 : (blockIdx.z == 1) ? i1 : i2;
  f16* hi = (blockIdx.z == 0) ? o0 : (blockIdx.z == 1) ? o1 : o2;
  __shared__ float t[32][33];
  int bx = blockIdx.x * 32, by = blockIdx.y * 32;
  int tx = threadIdx.x, ty = threadIdx.y;  // 32 x 8
  for (int i = 0; i < 32; i += 8) t[ty + i][tx] = in[(long)(by + ty + i) * n + bx + tx];
  __syncthreads();
  for (int i = 0; i < 32; i += 8)
    hi[(long)(bx + ty + i) * n + by + tx] = (f16)t[tx][ty + i];
}

// reduce 16 per-block-row partials -> final m, 1/l per column
__global__ void stats2(const float* __restrict__ pm, const float* __restrict__ pl,
                       float* __restrict__ mfo, float* __restrict__ rlo) {
  int c = blockIdx.x * 256 + threadIdx.x;  // b*2048 + k
  int b = c >> 11, k = c & 2047;
  float m = -1e30f;
  for (int qc = 0; qc < 16; ++qc) m = fmaxf(m, pm[(b * 16 + qc) * 2048 + k]);
  float l = 0.f;
  for (int qc = 0; qc < 16; ++qc)
    l += pl[(b * 16 + qc) * 2048 + k] * __expf(pm[(b * 16 + qc) * 2048 + k] - m);
  mfo[c] = m;
  rlo[c] = 1.f / l;
}

// in-place: S16 <- exp(S16 - m[col]) * rl[col]   (fp16)
__global__ __launch_bounds__(256) void norm(f16* __restrict__ S16,
                                            const float* __restrict__ mf,
                                            const float* __restrict__ rl) {
  long row = blockIdx.x;  // b*2048 + q
  int b = (int)(row >> 11);
  f16* Sr = S16 + row * 2048;
  const float* mb = mf + ((long)b << 11);
  const float* rb = rl + ((long)b << 11);
  int c = threadIdx.x * 8;
  f16x8 v = *(f16x8*)(Sr + c);
  float4 m0 = *(const float4*)(mb + c);
  float4 m1 = *(const float4*)(mb + c + 4);
  float4 r0 = *(const float4*)(rb + c);
  float4 r1 = *(const float4*)(rb + c + 4);
  f16x8 o;
  o[0] = (f16)(__expf((float)v[0] - m0.x) * r0.x);
  o[1] = (f16)(__expf((float)v[1] - m0.y) * r0.y);
  o[2] = (f16)(__expf((float)v[2] - m0.z) * r0.z);
  o[3] = (f16)(__expf((float)v[3] - m0.w) * r0.w);
  o[4] = (f16)(__expf((float)v[4] - m1.x) * r1.x);
  o[5] = (f16)(__expf((float)v[5] - m1.y) * r1.y);
  o[6] = (f16)(__expf((float)v[6] - m1.z) * r1.z);
  o[7] = (f16)(__expf((float)v[7] - m1.w) * r1.w);
  *(f16x8*)(Sr + c) = o;
}

extern "C" void kernel_launch(void* const* d_in, const int* in_sizes, int n_in,
                              void* d_out, int out_size, void* d_ws, size_t ws_size,
                              hipStream_t stream) {
  const float* query = (const float*)d_in[0];
  const float* key   = (const float*)d_in[1];
  const float* value = (const float*)d_in[2];
  const float* Wq    = (const float*)d_in[3];
  const float* Wk    = (const float*)d_in[4];
  const float* Wv    = (const float*)d_in[5];
  const float* Wo    = (const float*)d_in[6];
  float* out = (float*)d_out;

  // arena (f16-element offsets), ~144 MB
  f16* h = (f16*)d_ws;
  const long E8 = 8388608L;  // 8192*1024
  const long E1 = 1048576L;  // 1024*1024
  f16* q16   = h;            // contiguous A-batch for proj: q16,k16,v16
  f16* k16   = h + E8;
  f16* v16   = h + 2 * E8;
  f16* Qh    = h + 3 * E8;   // contiguous C-batch: Qh, Kh, VWoT
  f16* Kh    = h + 4 * E8;
  f16* VWoT  = h + 5 * E8;   // [4][1024][2048]
  f16* Wqt   = h + 6 * E8;   // contiguous B-batch: Wqt, Wkt, Wvot
  f16* Wkt   = Wqt + E1;
  f16* Wvot  = Wkt + E1;
  f16* Wot   = Wvot + E1;
  f16* wv16  = Wot + E1;
  f16* S16   = wv16 + E1;    // [4][2048][2048] fp16 scores -> attn (in place)
  float* pm  = (float*)(S16 + 16777216L);  // [4][16][2048]
  float* pl  = pm + 131072;
  float* mf  = pl + 131072;  // 8192
  float* rl  = mf + 8192;
  (void)in_sizes; (void)n_in; (void)out_size; (void)ws_size;

  dim3 tb32(32, 8);
  tconv3<<<dim3(32, 32, 3), tb32, 0, stream>>>(Wq, Wk, Wo, Wqt, Wkt, Wot, 1024);
  convert1<<<512, 256, 0, stream>>>(Wv, wv16, E1);

  // Wvo^T = (Wv @ Wo)^T  (M=N=K=1024)
  gemm_wvo<<<dim3(8, 8, 1), 256, 0, stream>>>(wv16, Wot, Wvot, 1024, 1024, 1024, 1024);

  // fused input conversions (q,k,v)
  convert3<<<dim3(4096, 1, 3), 256, 0, stream>>>(query, key, value, q16, k16, v16, E8);

  // batched projections z=3: z0 Q=query@Wq, z1 K=key@Wk, z2 VWo=value@Wvo
  // (z2 written per-batch transposed: VWoT[b][e][s]) -- 1536 blocks
  gemm16<4, 0><<<dim3(8, 64, 3), 256, 0, stream>>>(
      q16, Wqt, nullptr, Qh, nullptr, nullptr,
      1024, 1024, 1024, 1024, E8, E1, E8, 1.f);

  // scores = 0.125 * Q K^T per batch, fp16 out + fused column stats -- 1024 blocks
  gemm16<2, 1><<<dim3(16, 16, 4), 256, 0, stream>>>(
      Qh, Kh, nullptr, S16, pm, pl,
      1024, 1024, 1024, 2048, 2097152L, 2097152L, 4194304L, 0.125f);

  // reduce partials, then normalize in place
  stats2<<<32, 256, 0, stream>>>(pm, pl, mf, rl);
  norm<<<8192, 256, 0, stream>>>(S16, mf, rl);

  // out = attn @ VWo per batch (M=2048, N=1024, K=2048), fp32 out -- 512 blocks
  gemm16<0, 0><<<dim3(8, 16, 4), 256, 0, stream>>>(
      S16, VWoT, out, nullptr, nullptr, nullptr,
      2048, 2048, 2048, 1024, 4194304L, 2097152L, 2097152L, 1.f);
}

// Round 11
// 252.959 us; speedup vs baseline: 1.1290x; 1.0453x over previous
//
#include <hip/hip_runtime.h>

// B=4, S=2048, D=E=1024, DIM=64 -> scale 0.125
// softmax quirk: normalized over the QUERY axis:
//   attn[b,q,k] = exp(s[b,q,k] - m[b,k]) / sum_q' exp(s[b,q',k] - m[b,k])
//
// R11: R10 consolidation. 2-phase 128x128 BK=64 conflict-free gemm16 for all
// GEMMs; XCD swizzle ONLY on scores/final (panel reuse) — proj measured
// faster without (R6 90.5 vs R10 103 us). Column stats fused in scores
// epilogue; z-batched converts. Pipeline: Wvo=Wv@Wo fold; batched {Q,K,VWo}
// proj; fp16 scores (+stats); stats2; in-place norm; final attn@VWo.

typedef _Float16 f16;
typedef _Float16 f16x8 __attribute__((ext_vector_type(8)));
typedef float f32x4 __attribute__((ext_vector_type(4)));

__device__ __forceinline__ void gl_lds16(const void* g, void* l) {
  __builtin_amdgcn_global_load_lds(
      (const __attribute__((address_space(1))) void*)(uintptr_t)g,
      (__attribute__((address_space(3))) void*)(uint32_t)(uintptr_t)l, 16, 0, 0);
}

// bijective XCD-chunked swizzle (m204): consecutive work ids -> same XCD
__device__ __forceinline__ int xcd_swz(int F, int nwg) {
  int q = nwg >> 3, r = nwg & 7;
  int xcd = F & 7, idx = F >> 3;
  return (xcd < r ? xcd * (q + 1) : r * (q + 1) + (xcd - r) * q) + idx;
}

// C[M,N] = scale * A[M,K]*B[N,K]^T  (NT, fp16 operands, fp32 accum)
// EPI: 0 = fp32 C; 2 = fp16 C; 4 = fp16 C, z==2 written per-batch transposed
//      (projection batch: Q, K, VWo^T).
// STATS: fused per-block column stats (max, sumexp over the 128 q-rows).
// SWZ: XCD-chunked block swizzle on/off.
template <int EPI, int STATS, int SWZ>
__global__ __launch_bounds__(256) void gemm16(
    const f16* __restrict__ Ag, const f16* __restrict__ Bg,
    float* __restrict__ Cf, f16* __restrict__ Ch,
    float* __restrict__ pm, float* __restrict__ pl,
    int K, int ldA, int ldB, int ldC, long sA, long sB, long sC, float scale) {
  __shared__ f16 sA_[128 * 64];
  __shared__ f16 sB_[128 * 64];

  const int tid = threadIdx.x;
  const int lane = tid & 63;
  const int wave = tid >> 6;
  int bx, by;
  long bz;
  if constexpr (SWZ) {
    const int gx = gridDim.x, gy = gridDim.y;
    const int nwg = gx * gy * gridDim.z;
    int F = blockIdx.x + gx * (blockIdx.y + gy * blockIdx.z);
    int wg = xcd_swz(F, nwg);
    bx = wg % gx;
    by = (wg / gx) % gy;
    bz = wg / (gx * gy);
  } else {
    bx = blockIdx.x;
    by = blockIdx.y;
    bz = blockIdx.z;
  }

  const int tM = by * 128;
  const int tN = bx * 128;
  const int wr = (wave >> 1) * 64;
  const int wc = (wave & 1) * 64;
  const int r16 = lane & 15;
  const int q4 = lane >> 4;

  const f16* Abase = Ag + bz * sA;
  const f16* Bbase = Bg + bz * sB;

  f32x4 acc[4][4] = {};

  for (int kt = 0; kt < K; kt += 64) {
    // stage A,B tiles [128][64]; LDS linear dest, source col pre-swizzled
#pragma unroll
    for (int it = 0; it < 4; ++it) {
      int row = it * 32 + (tid >> 3);
      int s = tid & 7;
      int gcol = kt + ((s ^ (row & 7)) << 3);
      int lo = row * 64 + s * 8;
      gl_lds16(Abase + (long)(tM + row) * ldA + gcol, sA_ + lo);
      gl_lds16(Bbase + (long)(tN + row) * ldB + gcol, sB_ + lo);
    }
    __syncthreads();
#pragma unroll
    for (int kk = 0; kk < 2; ++kk) {
      f16x8 ah[4], bh[4];
#pragma unroll
      for (int m = 0; m < 4; ++m) {
        int ar = wr + m * 16 + r16;
        ah[m] = *(const f16x8*)(sA_ + ar * 64 + (((kk * 4 + q4) ^ (ar & 7)) << 3));
      }
#pragma unroll
      for (int n = 0; n < 4; ++n) {
        int br = wc + n * 16 + r16;
        bh[n] = *(const f16x8*)(sB_ + br * 64 + (((kk * 4 + q4) ^ (br & 7)) << 3));
      }
#pragma unroll
      for (int m = 0; m < 4; ++m)
#pragma unroll
        for (int n = 0; n < 4; ++n)
          acc[m][n] = __builtin_amdgcn_mfma_f32_16x16x32_f16(ah[m], bh[n], acc[m][n], 0, 0, 0);
    }
    __syncthreads();
  }

  // C write
#pragma unroll
  for (int m = 0; m < 4; ++m)
#pragma unroll
    for (int n = 0; n < 4; ++n)
#pragma unroll
      for (int j = 0; j < 4; ++j) {
        int rr = tM + wr + m * 16 + q4 * 4 + j;
        int cc = tN + wc + n * 16 + r16;
        float v = acc[m][n][j] * scale;
        if constexpr (EPI == 0) {
          Cf[bz * sC + (long)rr * ldC + cc] = v;
        } else if constexpr (EPI == 2) {
          Ch[bz * sC + (long)rr * ldC + cc] = (f16)v;
        } else {  // EPI == 4: projection batch
          if (bz == 2)
            Ch[2 * sC + (long)cc * 2048 + (long)(rr >> 11) * 2097152L + (rr & 2047)] = (f16)v;
          else
            Ch[bz * sC + (long)rr * ldC + cc] = (f16)v;
        }
      }

  if constexpr (STATS) {
    // per-block column stats over the 128 rows, for 128 cols.
    float* mbuf = (float*)sA_;  // [2][128]
    float* lbuf = mbuf + 256;
    const int wrIdx = wave >> 1, c0 = wc;
#pragma unroll
    for (int n = 0; n < 4; ++n) {
      float mt = -1e30f;
#pragma unroll
      for (int m = 0; m < 4; ++m)
#pragma unroll
        for (int j = 0; j < 4; ++j) mt = fmaxf(mt, acc[m][n][j] * scale);
      float lt = 0.f;
#pragma unroll
      for (int m = 0; m < 4; ++m)
#pragma unroll
        for (int j = 0; j < 4; ++j) lt += __expf(acc[m][n][j] * scale - mt);
      // reduce over q4 (lanes xor 16, 32): online merge
#pragma unroll
      for (int d = 16; d <= 32; d <<= 1) {
        float mo = __shfl_xor(mt, d);
        float lo = __shfl_xor(lt, d);
        float mn = fmaxf(mt, mo);
        lt = lt * __expf(mt - mn) + lo * __expf(mo - mn);
        mt = mn;
      }
      if (q4 == 0) {
        int c = c0 + n * 16 + r16;
        mbuf[wrIdx * 128 + c] = mt;
        lbuf[wrIdx * 128 + c] = lt;
      }
    }
    __syncthreads();
    if (tid < 128) {
      float m0 = mbuf[tid], m1 = mbuf[128 + tid];
      float l0 = lbuf[tid], l1 = lbuf[128 + tid];
      float mn = fmaxf(m0, m1);
      float ln = l0 * __expf(m0 - mn) + l1 * __expf(m1 - mn);
      long idx = (bz * 16 + (tM >> 7)) * 2048 + tN + tid;
      pm[idx] = mn;
      pl[idx] = ln;
    }
  }
}

// small 128x128-tile GEMM for Wvo = (Wv @ Wo)^T  (fp16, transposed store)
__global__ __launch_bounds__(256) void gemm_wvo(
    const f16* __restrict__ Ag, const f16* __restrict__ Bg, f16* __restrict__ Ch,
    int K, int ldA, int ldB, int ldC) {
  __shared__ f16 sA_[128 * 64];
  __shared__ f16 sB_[128 * 64];
  const int tid = threadIdx.x;
  const int lane = tid & 63;
  const int wave = tid >> 6;
  const int tM = blockIdx.y * 128;
  const int tN = blockIdx.x * 128;
  const int wr = (wave >> 1) * 64;
  const int wc = (wave & 1) * 64;
  const int r16 = lane & 15;
  const int q4 = lane >> 4;
  f32x4 acc[4][4] = {};
  for (int kt = 0; kt < K; kt += 64) {
#pragma unroll
    for (int it = 0; it < 4; ++it) {
      int row = it * 32 + (tid >> 3);
      int s = tid & 7;
      int gcol = kt + ((s ^ (row & 7)) << 3);
      int lo = row * 64 + s * 8;
      gl_lds16(Ag + (long)(tM + row) * ldA + gcol, sA_ + lo);
      gl_lds16(Bg + (long)(tN + row) * ldB + gcol, sB_ + lo);
    }
    __syncthreads();
#pragma unroll
    for (int kk = 0; kk < 2; ++kk) {
      f16x8 ah[4], bh[4];
#pragma unroll
      for (int m = 0; m < 4; ++m) {
        int ar = wr + m * 16 + r16;
        ah[m] = *(const f16x8*)(sA_ + ar * 64 + (((kk * 4 + q4) ^ (ar & 7)) << 3));
      }
#pragma unroll
      for (int n = 0; n < 4; ++n) {
        int br = wc + n * 16 + r16;
        bh[n] = *(const f16x8*)(sB_ + br * 64 + (((kk * 4 + q4) ^ (br & 7)) << 3));
      }
#pragma unroll
      for (int m = 0; m < 4; ++m)
#pragma unroll
        for (int n = 0; n < 4; ++n)
          acc[m][n] = __builtin_amdgcn_mfma_f32_16x16x32_f16(ah[m], bh[n], acc[m][n], 0, 0, 0);
    }
    __syncthreads();
  }
#pragma unroll
  for (int m = 0; m < 4; ++m)
#pragma unroll
    for (int n = 0; n < 4; ++n)
#pragma unroll
      for (int j = 0; j < 4; ++j) {
        int rr = tM + wr + m * 16 + q4 * 4 + j;
        int cc = tN + wc + n * 16 + r16;
        Ch[(long)cc * ldC + rr] = (f16)acc[m][n][j];
      }
}

// fused fp32 -> fp16 conversion for q,k,v,Wv (z selects buffer; z=3 smaller)
__global__ __launch_bounds__(256) void convert4(
    const float* __restrict__ i0, const float* __restrict__ i1,
    const float* __restrict__ i2, const float* __restrict__ i3,
    f16* __restrict__ o0, f16* __restrict__ o1, f16* __restrict__ o2,
    f16* __restrict__ o3, long n012, long n3) {
  const int z = blockIdx.z;
  const float* in = (z == 0) ? i0 : (z == 1) ? i1 : (z == 2) ? i2 : i3;
  f16* hi = (z == 0) ? o0 : (z == 1) ? o1 : (z == 2) ? o2 : o3;
  long n = (z == 3) ? n3 : n012;
  long i = ((long)blockIdx.x * 256 + threadIdx.x) * 8;
  if (i >= n) return;
  float4 aa = *(const float4*)(in + i);
  float4 bb = *(const float4*)(in + i + 4);
  f16x8 h;
  h[0] = (f16)aa.x; h[1] = (f16)aa.y; h[2] = (f16)aa.z; h[3] = (f16)aa.w;
  h[4] = (f16)bb.x; h[5] = (f16)bb.y; h[6] = (f16)bb.z; h[7] = (f16)bb.w;
  *(f16x8*)(hi + i) = h;
}

// fused transpose + fp16 convert for Wq,Wk,Wo (z selects)
__global__ void tconv3(const float* __restrict__ i0, const float* __restrict__ i1,
                       const float* __restrict__ i2, f16* __restrict__ o0,
                       f16* __restrict__ o1, f16* __restrict__ o2, int n) {
  const float* in = (blockIdx.z == 0) ? i0 : (blockIdx.z == 1) ? i1 : i2;
  f16* hi = (blockIdx.z == 0) ? o0 : (blockIdx.z == 1) ? o1 : o2;
  __shared__ float t[32][33];
  int bx = blockIdx.x * 32, by = blockIdx.y * 32;
  int tx = threadIdx.x, ty = threadIdx.y;  // 32 x 8
  for (int i = 0; i < 32; i += 8) t[ty + i][tx] = in[(long)(by + ty + i) * n + bx + tx];
  __syncthreads();
  for (int i = 0; i < 32; i += 8)
    hi[(long)(bx + ty + i) * n + by + tx] = (f16)t[tx][ty + i];
}

// reduce 16 per-block-row partials -> final m, 1/l per column
__global__ void stats2(const float* __restrict__ pm, const float* __restrict__ pl,
                       float* __restrict__ mfo, float* __restrict__ rlo) {
  int c = blockIdx.x * 256 + threadIdx.x;  // b*2048 + k
  int b = c >> 11, k = c & 2047;
  float m = -1e30f;
  for (int qc = 0; qc < 16; ++qc) m = fmaxf(m, pm[(b * 16 + qc) * 2048 + k]);
  float l = 0.f;
  for (int qc = 0; qc < 16; ++qc)
    l += pl[(b * 16 + qc) * 2048 + k] * __expf(pm[(b * 16 + qc) * 2048 + k] - m);
  mfo[c] = m;
  rlo[c] = 1.f / l;
}

// in-place: S16 <- exp(S16 - m[col]) * rl[col]   (fp16)
__global__ __launch_bounds__(256) void norm(f16* __restrict__ S16,
                                            const float* __restrict__ mf,
                                            const float* __restrict__ rl) {
  long row = blockIdx.x;  // b*2048 + q
  int b = (int)(row >> 11);
  f16* Sr = S16 + row * 2048;
  const float* mb = mf + ((long)b << 11);
  const float* rb = rl + ((long)b << 11);
  int c = threadIdx.x * 8;
  f16x8 v = *(f16x8*)(Sr + c);
  float4 m0 = *(const float4*)(mb + c);
  float4 m1 = *(const float4*)(mb + c + 4);
  float4 r0 = *(const float4*)(rb + c);
  float4 r1 = *(const float4*)(rb + c + 4);
  f16x8 o;
  o[0] = (f16)(__expf((float)v[0] - m0.x) * r0.x);
  o[1] = (f16)(__expf((float)v[1] - m0.y) * r0.y);
  o[2] = (f16)(__expf((float)v[2] - m0.z) * r0.z);
  o[3] = (f16)(__expf((float)v[3] - m0.w) * r0.w);
  o[4] = (f16)(__expf((float)v[4] - m1.x) * r1.x);
  o[5] = (f16)(__expf((float)v[5] - m1.y) * r1.y);
  o[6] = (f16)(__expf((float)v[6] - m1.z) * r1.z);
  o[7] = (f16)(__expf((float)v[7] - m1.w) * r1.w);
  *(f16x8*)(Sr + c) = o;
}

extern "C" void kernel_launch(void* const* d_in, const int* in_sizes, int n_in,
                              void* d_out, int out_size, void* d_ws, size_t ws_size,
                              hipStream_t stream) {
  const float* query = (const float*)d_in[0];
  const float* key   = (const float*)d_in[1];
  const float* value = (const float*)d_in[2];
  const float* Wq    = (const float*)d_in[3];
  const float* Wk    = (const float*)d_in[4];
  const float* Wv    = (const float*)d_in[5];
  const float* Wo    = (const float*)d_in[6];
  float* out = (float*)d_out;

  // arena (f16-element offsets), ~144 MB
  f16* h = (f16*)d_ws;
  const long E8 = 8388608L;  // 8192*1024
  const long E1 = 1048576L;  // 1024*1024
  f16* q16   = h;            // contiguous A-batch for proj: q16,k16,v16
  f16* k16   = h + E8;
  f16* v16   = h + 2 * E8;
  f16* Qh    = h + 3 * E8;   // contiguous C-batch: Qh, Kh, VWoT
  f16* Kh    = h + 4 * E8;
  f16* VWoT  = h + 5 * E8;   // [4][1024][2048]
  f16* Wqt   = h + 6 * E8;   // contiguous B-batch: Wqt, Wkt, Wvot
  f16* Wkt   = Wqt + E1;
  f16* Wvot  = Wkt + E1;
  f16* Wot   = Wvot + E1;
  f16* wv16  = Wot + E1;
  f16* S16   = wv16 + E1;    // [4][2048][2048] fp16 scores -> attn (in place)
  float* pm  = (float*)(S16 + 16777216L);  // [4][16][2048]
  float* pl  = pm + 131072;
  float* mf  = pl + 131072;  // 8192
  float* rl  = mf + 8192;
  (void)in_sizes; (void)n_in; (void)out_size; (void)ws_size;

  dim3 tb32(32, 8);
  tconv3<<<dim3(32, 32, 3), tb32, 0, stream>>>(Wq, Wk, Wo, Wqt, Wkt, Wot, 1024);

  // fused input conversions (q,k,v,Wv)
  convert4<<<dim3(4096, 1, 4), 256, 0, stream>>>(query, key, value, Wv,
                                                 q16, k16, v16, wv16, E8, E1);

  // Wvo^T = (Wv @ Wo)^T  (M=N=K=1024)
  gemm_wvo<<<dim3(8, 8, 1), 256, 0, stream>>>(wv16, Wot, Wvot, 1024, 1024, 1024, 1024);

  // batched projections z=3: z0 Q=query@Wq, z1 K=key@Wk, z2 VWo=value@Wvo
  // (z2 written per-batch transposed: VWoT[b][e][s]) -- no swizzle (R10 A/B)
  gemm16<4, 0, 0><<<dim3(8, 64, 3), 256, 0, stream>>>(
      q16, Wqt, nullptr, Qh, nullptr, nullptr,
      1024, 1024, 1024, 1024, E8, E1, E8, 1.f);

  // scores = 0.125 * Q K^T per batch, fp16 out + fused column stats
  gemm16<2, 1, 1><<<dim3(16, 16, 4), 256, 0, stream>>>(
      Qh, Kh, nullptr, S16, pm, pl,
      1024, 1024, 1024, 2048, 2097152L, 2097152L, 4194304L, 0.125f);

  // reduce partials, then normalize in place
  stats2<<<32, 256, 0, stream>>>(pm, pl, mf, rl);
  norm<<<8192, 256, 0, stream>>>(S16, mf, rl);

  // out = attn @ VWo per batch (M=2048, N=1024, K=2048), fp32 out
  gemm16<0, 0, 1><<<dim3(8, 16, 4), 256, 0, stream>>>(
      S16, VWoT, out, nullptr, nullptr, nullptr,
      2048, 2048, 2048, 1024, 4194304L, 2097152L, 2097152L, 1.f);
}